// Round 10
// baseline (211.843 us; speedup 1.0000x reference)
//
#include <hip/hip_runtime.h>
#include <stdint.h>

// ---------------------------------------------------------------------------
// out = softmax((x Wq^T + bq)(x Wk^T + bk)^T / 8) (x Wk^T + bk) Wo^T + bo
// (v = k per the reference's faithful bug)
// B=8 S=1024 E=768 NH=12 D=64.  All GEMMs bf16-MFMA with fp32 accumulate.
//
// R18: sgemm_qk8 swizzle fix.  R17's counters exposed 1.77M LDS bank
// conflicts: the 1-bit st_16x32 flip left each ds_read_b128 (fixed ks) on
// banks 0-15 only (row stride 128B -> bank set = column; col ∈ {0,16,32,48}
// ^ {0,32}).  Now 3-bit swizzle byte_col ^= (row&7)<<4: col spans all 8
// 16B slots -> 32 banks, 2 rows/slot (2-way = free, m136).  Both sides
// updated consistently (stage source col + read flip + ks via XOR-64);
// bijective within each row -> bit-identical output.  All else = R17.
// ---------------------------------------------------------------------------

using short8   = __attribute__((ext_vector_type(8))) short;
using uint4v   = __attribute__((ext_vector_type(4))) unsigned;
using float4v  = __attribute__((ext_vector_type(4))) float;
using float16v = __attribute__((ext_vector_type(16))) float;

struct __align__(8) U2 { unsigned x, y; };

__device__ __forceinline__ void async16(void* lds, const void* g) {
  __builtin_amdgcn_global_load_lds(
      (const __attribute__((address_space(1))) void*)g,
      (__attribute__((address_space(3))) void*)lds, 16, 0, 0);
}

#define LGKM_WAIT  asm volatile("s_waitcnt lgkmcnt(0)" ::: "memory")
// bare workgroup barrier WITHOUT the vmcnt(0) drain __syncthreads forces:
// in-flight global_load_lds cross it untouched.
#define BARRIER    asm volatile("s_barrier" ::: "memory")

template <int N> __device__ __forceinline__ void vm_wait() {
  if constexpr (N == 4) asm volatile("s_waitcnt vmcnt(4)" ::: "memory");
  else if constexpr (N == 0) asm volatile("s_waitcnt vmcnt(0)" ::: "memory");
}

// fp32 -> bf16 bits, round-to-nearest-even
__device__ __forceinline__ unsigned bf16b(float f) {
  union { float f; unsigned u; } v; v.f = f;
  unsigned r = v.u + 0x7FFFu + ((v.u >> 16) & 1u);
  return r >> 16;
}
// RNE adjust only (bf16 = high 16 bits of result): 2 VALU
__device__ __forceinline__ unsigned rne_adj(float f) {
  union { float f; unsigned u; } v; v.f = f;
  return v.u + 0x7FFFu + ((v.u >> 16) & 1u);
}
// pack hi16(a):hi16(b) -> one v_perm_b32
__device__ __forceinline__ unsigned pack_hi16(unsigned a, unsigned b) {
  return __builtin_amdgcn_perm(a, b, 0x07060302u);
}
// packed fp32x2 -> bf16x2 (RNE), single instruction; lo = bf16(a), hi = bf16(b)
__device__ __forceinline__ unsigned cvt_pk_bf16(float a, float b) {
  unsigned r;
  asm("v_cvt_pk_bf16_f32 %0, %1, %2" : "=v"(r) : "v"(a), "v"(b));
  return r;
}

// ---------------------------------------------------------------------------
// fp32 -> bf16 bulk convert, x + the three weight matrices in ONE launch.
// blocks [0,3072): x (786432 f32x8 chunks, exact);  [3072,3936): weights.
// ---------------------------------------------------------------------------
__global__ __launch_bounds__(256) void cvt_all(
    const float* __restrict__ x, const float* __restrict__ w0,
    const float* __restrict__ w1, const float* __restrict__ w2,
    unsigned short* __restrict__ ox, unsigned short* __restrict__ o0,
    unsigned short* __restrict__ o1, unsigned short* __restrict__ o2) {
  const int bid = blockIdx.x;
  const float* in;
  unsigned short* out;
  int i;
  if (bid < 3072) {
    in = x; out = ox; i = bid * 256 + threadIdx.x;
  } else {
    int b2 = bid - 3072;           // 0..863, 288 blocks per matrix
    int mi = b2 / 288;
    in = (mi == 0) ? w0 : (mi == 1) ? w1 : w2;
    out = (mi == 0) ? o0 : (mi == 1) ? o1 : o2;
    i = (b2 - mi * 288) * 256 + threadIdx.x;
  }
  const float4v* p = (const float4v*)in;
  float4v a = p[i * 2], b = p[i * 2 + 1];
  uint4v w;
  w[0] = pack_hi16(rne_adj(a[1]), rne_adj(a[0]));
  w[1] = pack_hi16(rne_adj(a[3]), rne_adj(a[2]));
  w[2] = pack_hi16(rne_adj(b[1]), rne_adj(b[0]));
  w[3] = pack_hi16(rne_adj(b[3]), rne_adj(b[2]));
  ((uint4v*)out)[i] = w;
}

// ---------------------------------------------------------------------------
// One K-tile (BK=64) = 4 quadrant phases in order (0,0),(0,1),(1,1),(1,0).
// Per phase: ds_read frag subtile | stage half-tile(s) | BARRIER |
// lgkm(0)+sched_barrier | setprio(1) 16 MFMA setprio(0) | [vmcnt] | BARRIER.
// Frag reuse: A(Mh=0) read ph1 (reused ph2), B(Nh=0) ph1 (reused ph4 from
// regs), B(Nh=1) ph2 (reused ph3), A(Mh=1) ph3 -> 24 ds_read_b128/tile.
// LDS byte layout: buf*65536 + mat*32768 + half*16384 + row*128 + col*2,
// 3-bit swizzle: byte_col ^= ((row&7)<<4).  ks advance = XOR 64 (bit 6 is
// inside the swizzled field; Q4*16+ks*64 carries no bits past bit 6).
// ---------------------------------------------------------------------------
template <int BUF, int WAIT, class F1, class F2, class F3, class F4>
__device__ __forceinline__ void ktile4(const char* lds, int aoff, int boff,
                                       float4v (&acc)[2][2][2][4],
                                       F1&& s1, F2&& s2, F3&& s3, F4&& s4) {
  constexpr int AB = BUF * 65536;
  constexpr int BB = BUF * 65536 + 32768;
  short8 af[2][2], b0[4][2], b1[4][2];

#define RD_A(MH)                                                              \
  _Pragma("unroll") for (int mf = 0; mf < 2; ++mf)                            \
  _Pragma("unroll") for (int ks = 0; ks < 2; ++ks)                            \
    af[mf][ks] = *(const short8*)(lds + AB +                                  \
        (((MH)*16384 + aoff + mf*2048) ^ (ks*64)));
#define RD_B(NH, BF)                                                          \
  _Pragma("unroll") for (int nf = 0; nf < 4; ++nf)                            \
  _Pragma("unroll") for (int ks = 0; ks < 2; ++ks)                            \
    BF[nf][ks] = *(const short8*)(lds + BB +                                  \
        (((NH)*16384 + boff + nf*2048) ^ (ks*64)));
#define MM(MH, NH, BF)                                                        \
  _Pragma("unroll") for (int mf = 0; mf < 2; ++mf)                            \
  _Pragma("unroll") for (int nf = 0; nf < 4; ++nf)                            \
  _Pragma("unroll") for (int ks = 0; ks < 2; ++ks)                            \
    acc[MH][NH][mf][nf] = __builtin_amdgcn_mfma_f32_16x16x32_bf16(            \
        af[mf][ks], BF[nf][ks], acc[MH][NH][mf][nf], 0, 0, 0);

  // phase 1: quadrant (0,0)
  RD_A(0) RD_B(0, b0) s1();
  BARRIER; LGKM_WAIT; __builtin_amdgcn_sched_barrier(0);
  __builtin_amdgcn_s_setprio(1); MM(0, 0, b0) __builtin_amdgcn_s_setprio(0);
  BARRIER;
  // phase 2: quadrant (0,1)
  RD_B(1, b1) s2();
  BARRIER; LGKM_WAIT; __builtin_amdgcn_sched_barrier(0);
  __builtin_amdgcn_s_setprio(1); MM(0, 1, b1) __builtin_amdgcn_s_setprio(0);
  BARRIER;
  // phase 3: quadrant (1,1)
  RD_A(1) s3();
  BARRIER; LGKM_WAIT; __builtin_amdgcn_sched_barrier(0);
  __builtin_amdgcn_s_setprio(1); MM(1, 1, b1) __builtin_amdgcn_s_setprio(0);
  BARRIER;
  // phase 4: quadrant (1,0)
  s4();
  BARRIER; LGKM_WAIT; __builtin_amdgcn_sched_barrier(0);
  __builtin_amdgcn_s_setprio(1); MM(1, 0, b0) __builtin_amdgcn_s_setprio(0);
  vm_wait<WAIT>();
  BARRIER;
#undef RD_A
#undef RD_B
#undef MM
}

// ---------------------------------------------------------------------------
// QK-proj GEMM, 8-phase schedule: [q|k] = x[8192,768]*Wqk^T (+bias).
// 256x256 tile, BK=64, 12 K-tiles (6 iters x 2), 8 waves (4M x 2N,
// per-wave 64x128 out), 128 KB LDS dbuf, grid 192 = 1 block/CU.
// Staging: global_load_lds width 16, source pre-swizzled so the linear LDS
// dest lands 3-bit-swizzled; ds_read applies the same XOR (rule #21).
// Half-tile stage slots:
//   ph1: T(2i+1).{Ah1,Bh0}   ph3: T(2i+2).Ah0   ph4: T(2i+2).Bh1 + vmcnt(4)
//   ph5: T(2i+2).{Ah1,Bh0}   ph7: T(2i+3).Ah0   ph8: T(2i+3).Bh1 + vmcnt(4)
// XCD swizzle (m204, 192%8==0): each XCD gets a contiguous 4m x 6n chunk.
// Outputs: q bf16 (bias + 0.125*log2e folded), k bf16 row-major,
// kt bf16 [96][64][1024] perm s-order.
// ---------------------------------------------------------------------------
__global__ __launch_bounds__(512, 2) void sgemm_qk8(
    const unsigned short* __restrict__ A, const unsigned short* __restrict__ B,
    const float* __restrict__ bias0, const float* __restrict__ bias1,
    unsigned short* __restrict__ outq, unsigned short* __restrict__ outk,
    unsigned short* __restrict__ outkt) {
  extern __shared__ __align__(16) char lds[];  // 131072 B
  const int tid = threadIdx.x;
  const int w = tid >> 6, lane = tid & 63;
  const int Q4 = lane >> 4, r = lane & 15;
  const int wr = w & 3, wc = w >> 2;
  const int bid = blockIdx.x;
  const int wg = (bid & 7) * 24 + (bid >> 3);
  const int m0 = (wg / 6) * 256;
  const int n0 = (wg % 6) * 256;

  // staging: instr (w,j) covers 8 rows x 128 B; dest = linear base+lane*16,
  // so dest row&7 = lane>>3, dest col = (lane&7)*16 B.  Source pre-applies
  // the inverse 3-bit swizzle: col_src = ((lane&7) ^ (lane>>3)) * 16 B.
  const int srow = lane >> 3;
  const int scol = ((lane & 7) ^ (lane >> 3)) * 8;  // shorts

  auto stA = [&](int buf, int half, int t) {
#pragma unroll
    for (int j = 0; j < 2; ++j)
      async16(lds + buf * 65536 + half * 16384 + (w * 2 + j) * 1024 + lane * 16,
              A + (size_t)(m0 + half * 128 + (w * 2 + j) * 8 + srow) * 768 +
                  t * 64 + scol);
  };
  auto stB = [&](int buf, int half, int t) {
#pragma unroll
    for (int j = 0; j < 2; ++j)
      async16(lds + buf * 65536 + 32768 + half * 16384 + (w * 2 + j) * 1024 + lane * 16,
              B + (size_t)(n0 + half * 128 + (w * 2 + j) * 8 + srow) * 768 +
                  t * 64 + scol);
  };

  // frag-read lane offsets (bytes); read-side swizzle XOR = (row&7)<<4,
  // row&7 = r&7 for all frag rows (wr*32, wc*64, mf/nf*16 are mult of 8).
  const int flip = (r & 7) * 16;
  const int aoff = (wr * 32 + r) * 128 + ((Q4 * 16) ^ flip);
  const int boff = (wc * 64 + r) * 128 + ((Q4 * 16) ^ flip);

  float4v acc[2][2][2][4];  // [Mh][Nh][mf][nf]
#pragma unroll
  for (int a = 0; a < 2; ++a)
#pragma unroll
    for (int b = 0; b < 2; ++b)
#pragma unroll
      for (int c = 0; c < 2; ++c)
#pragma unroll
        for (int d = 0; d < 4; ++d)
#pragma unroll
          for (int g = 0; g < 4; ++g) acc[a][b][c][d][g] = 0.0f;

  // prologue: T0 complete + T1.{Ah0,Bh1}; vmcnt(4) leaves T1's 2 halves in
  // flight (T0 landed), matching the steady-state post-ph8 invariant.
  stA(0, 0, 0); stB(0, 0, 0); stB(0, 1, 0); stA(0, 1, 0);
  stA(1, 0, 1); stB(1, 1, 1);
  vm_wait<4>(); BARRIER;

#pragma unroll 1
  for (int i = 0; i < 5; ++i) {
    const int t1 = 2 * i + 1, t2 = 2 * i + 2, t3 = 2 * i + 3;
    ktile4<0, 4>(lds, aoff, boff, acc,
                 [&] { stA(1, 1, t1); stB(1, 0, t1); },
                 [&] {},
                 [&] { stA(0, 0, t2); },
                 [&] { stB(0, 1, t2); });
    ktile4<1, 4>(lds, aoff, boff, acc,
                 [&] { stA(0, 1, t2); stB(0, 0, t2); },
                 [&] {},
                 [&] { stA(1, 0, t3); },
                 [&] { stB(1, 1, t3); });
  }
  // tail: tiles 10 (buf0) and 11 (buf1); drain all staging before buf1 reads
  ktile4<0, 0>(lds, aoff, boff, acc,
               [&] { stA(1, 1, 11); stB(1, 0, 11); },
               [&] {}, [&] {}, [&] {});
  ktile4<1, -1>(lds, aoff, boff, acc, [&] {}, [&] {}, [&] {}, [&] {});

  // epilogue: C/D frag layout row = Q4*4+reg (M), col = r (N)
  const bool isq = (n0 < 768);  // 256-aligned n0 -> block-uniform
  const float* bias = isq ? bias0 : bias1;
  unsigned short* outp = isq ? outq : outk;
  const int nb = isq ? n0 : (n0 - 768);
  // q scale: 1/8 softmax * log2(e) so attention uses native exp2 (exact id)
  const float scl = isq ? 0.18033688011112042f : 1.0f;
#pragma unroll
  for (int Nh = 0; Nh < 2; ++Nh)
#pragma unroll
    for (int nf = 0; nf < 4; ++nf) {
      const int n = nb + Nh * 128 + wc * 64 + nf * 16 + r;
      const float bv = bias[n];
#pragma unroll
      for (int Mh = 0; Mh < 2; ++Mh)
#pragma unroll
        for (int mf = 0; mf < 2; ++mf) {
          const int m = m0 + Mh * 128 + wr * 32 + mf * 16 + Q4 * 4;
#pragma unroll
          for (int g = 0; g < 4; ++g)
            outp[(size_t)(m + g) * 768 + n] =
                (unsigned short)bf16b((acc[Mh][Nh][mf][nf][g] + bv) * scl);
        }
    }
  if (!isq) {
    // kt permuted write: slot(s) = (s&~15) + ((s>>2)&1)*8 + ((s>>3)&1)*4 + (s&3)
    const int bq = m0 >> 10;
    const int sb0 = (m0 & 1023) + wr * 32 + (Q4 & 1) * 8 + (Q4 >> 1) * 4;
#pragma unroll
    for (int Nh = 0; Nh < 2; ++Nh)
#pragma unroll
      for (int nf = 0; nf < 4; ++nf) {
        const int nk = nb + Nh * 128 + wc * 64 + nf * 16 + r;
        const int hh = nk >> 6, dd = nk & 63;
        const float bv = bias1[nk];
#pragma unroll
        for (int Mh = 0; Mh < 2; ++Mh)
#pragma unroll
          for (int mf = 0; mf < 2; ++mf) {
            const int ns = sb0 + Mh * 128 + mf * 16;
            const float4v a4 = acc[Mh][Nh][mf][nf];
            unsigned lo = pack_hi16(rne_adj(a4[1] + bv), rne_adj(a4[0] + bv));
            unsigned hi = pack_hi16(rne_adj(a4[3] + bv), rne_adj(a4[2] + bv));
            *(U2*)(outkt + (size_t)((bq * 12 + hh) * 64 + dd) * 1024 + ns) =
                U2{lo, hi};
          }
      }
  }
}

// ---------------------------------------------------------------------------
// Out-proj GEMM, register-prefetch pipeline: out = ao*Wo^T + bo (fp32).
// 64x128 tile, BK=64, 12 iters, grid (6,128) = 768 blocks, 4 waves, 24 KB LDS.
// ---------------------------------------------------------------------------
__global__ __launch_bounds__(256, 3) void sgemm_out(
    const unsigned short* __restrict__ A, const unsigned short* __restrict__ B,
    const float* __restrict__ bias, float* __restrict__ outp) {
  __shared__ __align__(16) unsigned short a_l[4096];  // 64 rows x 64 k
  __shared__ __align__(16) unsigned short b_l[8192];  // 128 rows x 64 k
  const int tid = threadIdx.x;
  const int w = tid >> 6, lane = tid & 63;
  const int Q4 = lane >> 4, r = lane & 15;
  const int m0 = blockIdx.y * 64;
  const int n0 = blockIdx.x * 128;
  const int wm = w >> 1, wn = w & 1;

  float4v acc[2][4];
#pragma unroll
  for (int i = 0; i < 2; ++i)
#pragma unroll
    for (int j = 0; j < 4; ++j)
#pragma unroll
      for (int g = 0; g < 4; ++g) acc[i][j][g] = 0.0f;

  const unsigned short* Ab = A + (size_t)(m0 + r) * 768 + Q4 * 8;
  const unsigned short* Bb = B + (size_t)(n0 + r) * 768 + Q4 * 8;

  uint4v ra[2], rb[4];
  auto gload = [&](int kt) {
#pragma unroll
    for (int ci = 0; ci < 2; ++ci) {
      int idx = w * 2 + ci;
      ra[ci] = *(const uint4v*)(Ab + (idx >> 1) * 12288 + kt + (idx & 1) * 32);
    }
#pragma unroll
    for (int ci = 0; ci < 4; ++ci) {
      int idx = w * 4 + ci;
      rb[ci] = *(const uint4v*)(Bb + (idx >> 1) * 12288 + kt + (idx & 1) * 32);
    }
  };
  auto swrite = [&]() {
#pragma unroll
    for (int ci = 0; ci < 2; ++ci) {
      int idx = w * 2 + ci;
      *(uint4v*)&a_l[idx * 512 + lane * 8] = ra[ci];
    }
#pragma unroll
    for (int ci = 0; ci < 4; ++ci) {
      int idx = w * 4 + ci;
      *(uint4v*)&b_l[idx * 512 + lane * 8] = rb[ci];
    }
  };

  short8 af[2][2], bf[4][2];
  auto loadf = [&]() {
#pragma unroll
    for (int i = 0; i < 2; ++i)
#pragma unroll
      for (int ks = 0; ks < 2; ++ks)
        af[i][ks] = *(const short8*)&a_l[((wm * 2 + i) * 2 + ks) * 512 + lane * 8];
#pragma unroll
    for (int i = 0; i < 4; ++i)
#pragma unroll
      for (int ks = 0; ks < 2; ++ks)
        bf[i][ks] = *(const short8*)&b_l[((wn * 4 + i) * 2 + ks) * 512 + lane * 8];
  };
  auto dot = [&]() {
#pragma unroll
    for (int mt = 0; mt < 2; ++mt)
#pragma unroll
      for (int nt = 0; nt < 4; ++nt)
#pragma unroll
        for (int ks = 0; ks < 2; ++ks)
          acc[mt][nt] = __builtin_amdgcn_mfma_f32_16x16x32_bf16(
              af[mt][ks], bf[nt][ks], acc[mt][nt], 0, 0, 0);
  };

  gload(0);
#pragma unroll 1
  for (int t = 0; t < 12; ++t) {
    if (t > 0) BARRIER;
    swrite();
    if (t < 11) gload(t * 64 + 64);
    LGKM_WAIT;
    BARRIER;
    loadf();
    dot();
  }

#pragma unroll
  for (int nt = 0; nt < 4; ++nt) {
    int n = n0 + wn * 64 + nt * 16 + r;
    float bv = bias[n];
#pragma unroll
    for (int mt = 0; mt < 2; ++mt) {
      int m = m0 + wm * 32 + mt * 16 + Q4 * 4;
#pragma unroll
      for (int g = 0; g < 4; ++g)
        outp[(size_t)(m + g) * 768 + n] = acc[mt][nt][g] + bv;
    }
  }
}

// ---------------------------------------------------------------------------
// Flash attention, v = k, no-max softmax (scores bounded; exactly equivalent;
// q pre-scaled by 0.125*log2e so P = exp2(Sc) natively).
// Block = (b, h, 128 q-rows), 4 waves; wave owns 32 q-cols end-to-end.
// Sc^T = K * Q^T via 32x32x16 MFMA (C: col=q=lane&31, row=s=(reg&3)+8*(reg>>2)+4*hi)
// P = exp2(Sc) via raw v_exp_f32; v_cvt_pk_bf16_f32 pack into PV B-fragment.
// O^T = V^T * P^T.  l = 4 accumulator chains + deferred single shfl_xor.
// Q loads straight to bfq registers (R17); LDS 32KB; R12 counted-vmcnt
// schedule.  Ledger: entering iter t: [Vt(t):4]; after K-stage: vmcnt(4)
// lands Vt(t) before PV; after Vt-stage: vmcnt(4) lands K(t+1) before next
// QK.  t=7 drains Vt(7) with vmcnt(0).  T5 setprio around MFMAs.
// ---------------------------------------------------------------------------
__global__ __launch_bounds__(256, 3) void attn_fused(
    const unsigned short* __restrict__ qg,   // [8192][768], scaled bf16
    const unsigned short* __restrict__ kg,   // [8192][768]
    const unsigned short* __restrict__ ktg,  // [96][64][1024] perm s-order
    unsigned short* __restrict__ ao) {       // [8192][768]
  __shared__ __align__(16) unsigned short k_l[8192];   // 16 KB: 128s x 64d
  __shared__ __align__(16) unsigned short vt_l[8192];  // 16 KB: 64d x 128s(perm)

  const int tid = threadIdx.x;
  const int w = tid >> 6, lane = tid & 63;
  const int l31 = lane & 31, hi = lane >> 5;
  const int bid = blockIdx.x;
  const int b = bid & 7;                 // XCD-aligned: one batch per XCD
  const int h = bid >> 6;                // 0..11, slow -> L2 working set small
  const int qt = (bid >> 3) & 7;
  const int q0 = qt * 128;
  const int bh = b * 12 + h;

  // Q direct to registers (identity of the old q_l round-trip):
  short8 bfq[4];
  {
    const unsigned short* qp =
        qg + (size_t)(b * 1024 + q0 + w * 32 + l31) * 768 + h * 64 + hi * 8;
#pragma unroll
    for (int kb = 0; kb < 4; ++kb)
      bfq[kb] = *(const short8*)(qp + kb * 16);
  }

  // stage first K/Vt tiles; one-time full drain
#pragma unroll
  for (int ci = 0; ci < 4; ++ci) {
    int c = w * 4 + ci;
    async16(&k_l[c * 512 + lane * 8],
            kg + ((size_t)(b * 1024 + (c >> 2) * 32 + l31) * 768 + h * 64 + (c & 3) * 16 + hi * 8));
    async16(&vt_l[c * 512 + lane * 8],
            ktg + ((size_t)(bh * 64 + (c >> 3) * 32 + l31) * 1024 + (c & 7) * 16 + hi * 8));
  }
  __syncthreads();

  float16v o_acc[2];
#pragma unroll
  for (int db = 0; db < 2; ++db)
#pragma unroll
    for (int e = 0; e < 16; ++e) o_acc[db][e] = 0.0f;
  float ps0 = 0.0f, ps1 = 0.0f, ps2 = 0.0f, ps3 = 0.0f;

#pragma unroll 1
  for (int it = 0; it < 8; ++it) {
    // ---- QK phase: Sc^T = K * Q^T, 128 s x 32 q, 16 MFMA, 16 ds_read_b128
    float16v sc[4];
#pragma unroll
    for (int sb = 0; sb < 4; ++sb)
#pragma unroll
      for (int e = 0; e < 16; ++e) sc[sb][e] = 0.0f;
    __builtin_amdgcn_s_setprio(1);
#pragma unroll
    for (int sb = 0; sb < 4; ++sb)
#pragma unroll
      for (int kb = 0; kb < 4; ++kb) {
        short8 af = *(const short8*)&k_l[(sb * 4 + kb) * 512 + lane * 8];
        sc[sb] = __builtin_amdgcn_mfma_f32_32x32x16_bf16(af, bfq[kb], sc[sb], 0, 0, 0);
      }
    __builtin_amdgcn_s_setprio(0);

    BARRIER;  // all waves done reading k_l(it)
    if (it < 7) {
      const int s1 = (it + 1) * 128;
#pragma unroll
      for (int ci = 0; ci < 4; ++ci) {
        int c = w * 4 + ci;
        async16(&k_l[c * 512 + lane * 8],
                kg + ((size_t)(b * 1024 + s1 + (c >> 2) * 32 + l31) * 768 + h * 64 + (c & 3) * 16 + hi * 8));
      }
      vm_wait<4>();  // retires Vt(it); K(it+1) stays in flight
    } else {
      vm_wait<0>();  // drain Vt(7)
    }
    BARRIER;  // all waves' Vt(it) landed -> PV reads safe

    // ---- exp + PV phase: P = exp2(Sc); O^T += V^T * P^T (reads vt_l(it))
#pragma unroll
    for (int sb = 0; sb < 4; ++sb) {
      float pe[16];
#pragma unroll
      for (int e = 0; e < 16; ++e) pe[e] = __builtin_amdgcn_exp2f(sc[sb][e]);
#pragma unroll
      for (int e = 0; e < 16; e += 4) {
        ps0 += pe[e]; ps1 += pe[e + 1]; ps2 += pe[e + 2]; ps3 += pe[e + 3];
      }
      uint4v w0, w1;
#pragma unroll
      for (int p = 0; p < 4; ++p) {
        w0[p] = cvt_pk_bf16(pe[2 * p], pe[2 * p + 1]);
        w1[p] = cvt_pk_bf16(pe[2 * p + 8], pe[2 * p + 9]);
      }
      short8 pf0 = __builtin_bit_cast(short8, w0);
      short8 pf1 = __builtin_bit_cast(short8, w1);
      __builtin_amdgcn_s_setprio(1);
#pragma unroll
      for (int db = 0; db < 2; ++db) {
        short8 vf0 = *(const short8*)&vt_l[(db * 8 + sb * 2) * 512 + lane * 8];
        o_acc[db] = __builtin_amdgcn_mfma_f32_32x32x16_bf16(vf0, pf0, o_acc[db], 0, 0, 0);
        short8 vf1 = *(const short8*)&vt_l[(db * 8 + sb * 2 + 1) * 512 + lane * 8];
        o_acc[db] = __builtin_amdgcn_mfma_f32_32x32x16_bf16(vf1, pf1, o_acc[db], 0, 0, 0);
      }
      __builtin_amdgcn_s_setprio(0);
    }

    if (it < 7) {
      BARRIER;  // all waves done reading vt_l(it)
      const int s1 = (it + 1) * 128;
#pragma unroll
      for (int ci = 0; ci < 4; ++ci) {
        int c = w * 4 + ci;
        async16(&vt_l[c * 512 + lane * 8],
                ktg + ((size_t)(bh * 64 + (c >> 3) * 32 + l31) * 1024 + s1 + (c & 7) * 16 + hi * 8));
      }
      vm_wait<4>();  // retires K(it+1); Vt(it+1) stays in flight
      BARRIER;       // all waves' K(it+1) landed -> next QK safe
    }
  }

  // l: hi-halves hold complementary s-rows -> one xor-32 completes the sum
  float ps = (ps0 + ps1) + (ps2 + ps3);
  ps += __shfl_xor(ps, 32, 64);
  const float inv = 1.0f / ps;
  const size_t rowbase = (size_t)(b * 1024 + q0 + w * 32 + l31) * 768 + h * 64;
#pragma unroll
  for (int db = 0; db < 2; ++db)
#pragma unroll
    for (int qq = 0; qq < 4; ++qq) {
      unsigned lo = cvt_pk_bf16(o_acc[db][qq * 4 + 0] * inv,
                                o_acc[db][qq * 4 + 1] * inv);
      unsigned hh = cvt_pk_bf16(o_acc[db][qq * 4 + 2] * inv,
                                o_acc[db][qq * 4 + 3] * inv);
      *(U2*)(ao + rowbase + db * 32 + qq * 8 + hi * 4) = U2{lo, hh};
    }
}

// ---------------------------------------------------------------------------
extern "C" void kernel_launch(void* const* d_in, const int* in_sizes, int n_in,
                              void* d_out, int out_size, void* d_ws, size_t ws_size,
                              hipStream_t stream) {
  const float* x  = (const float*)d_in[0];
  const float* Wq = (const float*)d_in[1];
  const float* bq = (const float*)d_in[2];
  const float* Wk = (const float*)d_in[3];
  const float* bk = (const float*)d_in[4];
  const float* Wo = (const float*)d_in[5];
  const float* bo = (const float*)d_in[6];
  (void)in_sizes; (void)n_in; (void)out_size; (void)ws_size;

  // allow 128 KB dynamic LDS for sgemm_qk8 (one-time; host-side, capture-safe)
  static bool inited = false;
  if (!inited) {
    (void)hipFuncSetAttribute((const void*)sgemm_qk8,
                              hipFuncAttributeMaxDynamicSharedMemorySize, 131072);
    inited = true;
  }

  char* ws = (char*)d_ws;
  unsigned short* x_b   = (unsigned short*)(ws);              // 12,582,912 B
  unsigned short* wqk_b = (unsigned short*)(ws + 12582912);   //  2,359,296 B  [Wq;Wk]
  unsigned short* wo_b  = (unsigned short*)(ws + 14942208);   //  1,179,648 B
  unsigned short* q_b   = (unsigned short*)(ws + 16121856);   // 12,582,912 B
  unsigned short* k_b   = (unsigned short*)(ws + 28704768);   // 12,582,912 B
  unsigned short* kt_b  = (unsigned short*)(ws + 41287680);   // 12,582,912 B
  unsigned short* ao_b  = (unsigned short*)(ws + 53870592);   // 12,582,912 B

  // x + all three weight matrices in one launch
  cvt_all<<<3936, 256, 0, stream>>>(x, Wq, Wk, Wo,
                                    x_b, wqk_b, wqk_b + 589824, wo_b);

  // q = (x Wq^T + bq)*0.125*log2e (bf16), k = x Wk^T + bk (row-major + perm kt)
  sgemm_qk8<<<192, 512, 131072, stream>>>(x_b, wqk_b, bq, bk, q_b, k_b, kt_b);
  attn_fused<<<768, 256, 0, stream>>>(q_b, k_b, kt_b, ao_b);
  // out = ao Wo^T + bo (fp32)
  sgemm_out<<<dim3(6, 128), 256, 0, stream>>>(ao_b, wo_b, bo, (float*)d_out);
}

// Round 11
// 187.555 us; speedup vs baseline: 1.1295x; 1.1295x over previous
//
#include <hip/hip_runtime.h>
#include <stdint.h>

// ---------------------------------------------------------------------------
// out = softmax((x Wq^T + bq)(x Wk^T + bk)^T / 8) (x Wk^T + bk) Wo^T + bo
// (v = k per the reference's faithful bug)
// B=8 S=1024 E=768 NH=12 D=64.  All GEMMs bf16-MFMA with fp32 accumulate.
//
// R19 = exact revert to R17 (best measured: 188.1 us).  R18's 3-bit LDS
// swizzle zeroed bank conflicts (1.77M -> 0) but cost +21 us: permuted
// per-lane gload_lds source addresses defeat DMA coalescing (FETCH +6MB,
// WRITE +12.6MB).  Conflicts are <=9% of sgemm_qk8 cycles -> accepted.
// Banked rules: (1) gload_lds source must stay lane-monotonic; (2) this
// workload's kernels are convoy/latency-bound, and every structural
// restructure beyond R17's state has regressed (R11/R13/R16/R18).
// ---------------------------------------------------------------------------

using short8   = __attribute__((ext_vector_type(8))) short;
using uint4v   = __attribute__((ext_vector_type(4))) unsigned;
using float4v  = __attribute__((ext_vector_type(4))) float;
using float16v = __attribute__((ext_vector_type(16))) float;

struct __align__(8) U2 { unsigned x, y; };

__device__ __forceinline__ void async16(void* lds, const void* g) {
  __builtin_amdgcn_global_load_lds(
      (const __attribute__((address_space(1))) void*)g,
      (__attribute__((address_space(3))) void*)lds, 16, 0, 0);
}

#define LGKM_WAIT  asm volatile("s_waitcnt lgkmcnt(0)" ::: "memory")
// bare workgroup barrier WITHOUT the vmcnt(0) drain __syncthreads forces:
// in-flight global_load_lds cross it untouched.
#define BARRIER    asm volatile("s_barrier" ::: "memory")

template <int N> __device__ __forceinline__ void vm_wait() {
  if constexpr (N == 4) asm volatile("s_waitcnt vmcnt(4)" ::: "memory");
  else if constexpr (N == 0) asm volatile("s_waitcnt vmcnt(0)" ::: "memory");
}

// fp32 -> bf16 bits, round-to-nearest-even
__device__ __forceinline__ unsigned bf16b(float f) {
  union { float f; unsigned u; } v; v.f = f;
  unsigned r = v.u + 0x7FFFu + ((v.u >> 16) & 1u);
  return r >> 16;
}
// RNE adjust only (bf16 = high 16 bits of result): 2 VALU
__device__ __forceinline__ unsigned rne_adj(float f) {
  union { float f; unsigned u; } v; v.f = f;
  return v.u + 0x7FFFu + ((v.u >> 16) & 1u);
}
// pack hi16(a):hi16(b) -> one v_perm_b32
__device__ __forceinline__ unsigned pack_hi16(unsigned a, unsigned b) {
  return __builtin_amdgcn_perm(a, b, 0x07060302u);
}
// packed fp32x2 -> bf16x2 (RNE), single instruction; lo = bf16(a), hi = bf16(b)
__device__ __forceinline__ unsigned cvt_pk_bf16(float a, float b) {
  unsigned r;
  asm("v_cvt_pk_bf16_f32 %0, %1, %2" : "=v"(r) : "v"(a), "v"(b));
  return r;
}

// ---------------------------------------------------------------------------
// fp32 -> bf16 bulk convert, x + the three weight matrices in ONE launch.
// blocks [0,3072): x (786432 f32x8 chunks, exact);  [3072,3936): weights.
// ---------------------------------------------------------------------------
__global__ __launch_bounds__(256) void cvt_all(
    const float* __restrict__ x, const float* __restrict__ w0,
    const float* __restrict__ w1, const float* __restrict__ w2,
    unsigned short* __restrict__ ox, unsigned short* __restrict__ o0,
    unsigned short* __restrict__ o1, unsigned short* __restrict__ o2) {
  const int bid = blockIdx.x;
  const float* in;
  unsigned short* out;
  int i;
  if (bid < 3072) {
    in = x; out = ox; i = bid * 256 + threadIdx.x;
  } else {
    int b2 = bid - 3072;           // 0..863, 288 blocks per matrix
    int mi = b2 / 288;
    in = (mi == 0) ? w0 : (mi == 1) ? w1 : w2;
    out = (mi == 0) ? o0 : (mi == 1) ? o1 : o2;
    i = (b2 - mi * 288) * 256 + threadIdx.x;
  }
  const float4v* p = (const float4v*)in;
  float4v a = p[i * 2], b = p[i * 2 + 1];
  uint4v w;
  w[0] = pack_hi16(rne_adj(a[1]), rne_adj(a[0]));
  w[1] = pack_hi16(rne_adj(a[3]), rne_adj(a[2]));
  w[2] = pack_hi16(rne_adj(b[1]), rne_adj(b[0]));
  w[3] = pack_hi16(rne_adj(b[3]), rne_adj(b[2]));
  ((uint4v*)out)[i] = w;
}

// ---------------------------------------------------------------------------
// One K-tile (BK=64) = 4 quadrant phases in order (0,0),(0,1),(1,1),(1,0).
// Per phase: ds_read frag subtile | stage half-tile(s) | BARRIER |
// lgkm(0)+sched_barrier | setprio(1) 16 MFMA setprio(0) | [vmcnt] | BARRIER.
// Frag reuse: A(Mh=0) read ph1 (reused ph2), B(Nh=0) ph1 (reused ph4 from
// regs), B(Nh=1) ph2 (reused ph3), A(Mh=1) ph3 -> 24 ds_read_b128/tile.
// LDS byte layout: buf*65536 + mat*32768 + half*16384 + row*128 + col*2,
// st_16x32 swizzled: byte ^= ((byte>>9)&1)<<5 (flip 32B half when row&4).
// ---------------------------------------------------------------------------
template <int BUF, int WAIT, class F1, class F2, class F3, class F4>
__device__ __forceinline__ void ktile4(const char* lds, int aoff, int boff,
                                       float4v (&acc)[2][2][2][4],
                                       F1&& s1, F2&& s2, F3&& s3, F4&& s4) {
  constexpr int AB = BUF * 65536;
  constexpr int BB = BUF * 65536 + 32768;
  short8 af[2][2], b0[4][2], b1[4][2];

#define RD_A(MH)                                                              \
  _Pragma("unroll") for (int mf = 0; mf < 2; ++mf)                            \
  _Pragma("unroll") for (int ks = 0; ks < 2; ++ks)                            \
    af[mf][ks] = *(const short8*)(lds + AB + (MH)*16384 + aoff + mf*2048 + ks*64);
#define RD_B(NH, BF)                                                          \
  _Pragma("unroll") for (int nf = 0; nf < 4; ++nf)                            \
  _Pragma("unroll") for (int ks = 0; ks < 2; ++ks)                            \
    BF[nf][ks] = *(const short8*)(lds + BB + (NH)*16384 + boff + nf*2048 + ks*64);
#define MM(MH, NH, BF)                                                        \
  _Pragma("unroll") for (int mf = 0; mf < 2; ++mf)                            \
  _Pragma("unroll") for (int nf = 0; nf < 4; ++nf)                            \
  _Pragma("unroll") for (int ks = 0; ks < 2; ++ks)                            \
    acc[MH][NH][mf][nf] = __builtin_amdgcn_mfma_f32_16x16x32_bf16(            \
        af[mf][ks], BF[nf][ks], acc[MH][NH][mf][nf], 0, 0, 0);

  // phase 1: quadrant (0,0)
  RD_A(0) RD_B(0, b0) s1();
  BARRIER; LGKM_WAIT; __builtin_amdgcn_sched_barrier(0);
  __builtin_amdgcn_s_setprio(1); MM(0, 0, b0) __builtin_amdgcn_s_setprio(0);
  BARRIER;
  // phase 2: quadrant (0,1)
  RD_B(1, b1) s2();
  BARRIER; LGKM_WAIT; __builtin_amdgcn_sched_barrier(0);
  __builtin_amdgcn_s_setprio(1); MM(0, 1, b1) __builtin_amdgcn_s_setprio(0);
  BARRIER;
  // phase 3: quadrant (1,1)
  RD_A(1) s3();
  BARRIER; LGKM_WAIT; __builtin_amdgcn_sched_barrier(0);
  __builtin_amdgcn_s_setprio(1); MM(1, 1, b1) __builtin_amdgcn_s_setprio(0);
  BARRIER;
  // phase 4: quadrant (1,0)
  s4();
  BARRIER; LGKM_WAIT; __builtin_amdgcn_sched_barrier(0);
  __builtin_amdgcn_s_setprio(1); MM(1, 0, b0) __builtin_amdgcn_s_setprio(0);
  vm_wait<WAIT>();
  BARRIER;
#undef RD_A
#undef RD_B
#undef MM
}

// ---------------------------------------------------------------------------
// QK-proj GEMM, 8-phase schedule: [q|k] = x[8192,768]*Wqk^T (+bias).
// 256x256 tile, BK=64, 12 K-tiles (6 iters x 2), 8 waves (4M x 2N,
// per-wave 64x128 out), 128 KB LDS dbuf, grid 192 = 1 block/CU.
// Staging: global_load_lds width 16, source pre-swizzled (st_16x32) so
// linear LDS dest lands swizzled; ds_read applies the same XOR (rule #21).
// Half-tile stage slots:
//   ph1: T(2i+1).{Ah1,Bh0}   ph3: T(2i+2).Ah0   ph4: T(2i+2).Bh1 + vmcnt(4)
//   ph5: T(2i+2).{Ah1,Bh0}   ph7: T(2i+3).Ah0   ph8: T(2i+3).Bh1 + vmcnt(4)
// XCD swizzle (m204, 192%8==0): each XCD gets a contiguous 4m x 6n chunk.
// Outputs: q bf16 (bias + 0.125*log2e folded), k bf16 row-major,
// kt bf16 [96][64][1024] perm s-order.
// ---------------------------------------------------------------------------
__global__ __launch_bounds__(512, 2) void sgemm_qk8(
    const unsigned short* __restrict__ A, const unsigned short* __restrict__ B,
    const float* __restrict__ bias0, const float* __restrict__ bias1,
    unsigned short* __restrict__ outq, unsigned short* __restrict__ outk,
    unsigned short* __restrict__ outkt) {
  extern __shared__ __align__(16) char lds[];  // 131072 B
  const int tid = threadIdx.x;
  const int w = tid >> 6, lane = tid & 63;
  const int Q4 = lane >> 4, r = lane & 15;
  const int wr = w & 3, wc = w >> 2;
  const int bid = blockIdx.x;
  const int wg = (bid & 7) * 24 + (bid >> 3);
  const int m0 = (wg / 6) * 256;
  const int n0 = (wg % 6) * 256;

  const int srow = lane >> 3;
  const int scol = ((lane & 7) * 8) ^ ((lane >> 5) * 16);  // shorts

  auto stA = [&](int buf, int half, int t) {
#pragma unroll
    for (int j = 0; j < 2; ++j)
      async16(lds + buf * 65536 + half * 16384 + (w * 2 + j) * 1024 + lane * 16,
              A + (size_t)(m0 + half * 128 + (w * 2 + j) * 8 + srow) * 768 +
                  t * 64 + scol);
  };
  auto stB = [&](int buf, int half, int t) {
#pragma unroll
    for (int j = 0; j < 2; ++j)
      async16(lds + buf * 65536 + 32768 + half * 16384 + (w * 2 + j) * 1024 + lane * 16,
              B + (size_t)(n0 + half * 128 + (w * 2 + j) * 8 + srow) * 768 +
                  t * 64 + scol);
  };

  const int flip = ((lane >> 2) & 1) * 32;
  const int aoff = (wr * 32 + r) * 128 + ((Q4 * 16) ^ flip);
  const int boff = (wc * 64 + r) * 128 + ((Q4 * 16) ^ flip);

  float4v acc[2][2][2][4];  // [Mh][Nh][mf][nf]
#pragma unroll
  for (int a = 0; a < 2; ++a)
#pragma unroll
    for (int b = 0; b < 2; ++b)
#pragma unroll
      for (int c = 0; c < 2; ++c)
#pragma unroll
        for (int d = 0; d < 4; ++d)
#pragma unroll
          for (int g = 0; g < 4; ++g) acc[a][b][c][d][g] = 0.0f;

  // prologue: T0 complete + T1.{Ah0,Bh1}; vmcnt(4) leaves T1's 2 halves in
  // flight (T0 landed), matching the steady-state post-ph8 invariant.
  stA(0, 0, 0); stB(0, 0, 0); stB(0, 1, 0); stA(0, 1, 0);
  stA(1, 0, 1); stB(1, 1, 1);
  vm_wait<4>(); BARRIER;

#pragma unroll 1
  for (int i = 0; i < 5; ++i) {
    const int t1 = 2 * i + 1, t2 = 2 * i + 2, t3 = 2 * i + 3;
    ktile4<0, 4>(lds, aoff, boff, acc,
                 [&] { stA(1, 1, t1); stB(1, 0, t1); },
                 [&] {},
                 [&] { stA(0, 0, t2); },
                 [&] { stB(0, 1, t2); });
    ktile4<1, 4>(lds, aoff, boff, acc,
                 [&] { stA(0, 1, t2); stB(0, 0, t2); },
                 [&] {},
                 [&] { stA(1, 0, t3); },
                 [&] { stB(1, 1, t3); });
  }
  // tail: tiles 10 (buf0) and 11 (buf1); drain all staging before buf1 reads
  ktile4<0, 0>(lds, aoff, boff, acc,
               [&] { stA(1, 1, 11); stB(1, 0, 11); },
               [&] {}, [&] {}, [&] {});
  ktile4<1, -1>(lds, aoff, boff, acc, [&] {}, [&] {}, [&] {}, [&] {});

  // epilogue: C/D frag layout row = Q4*4+reg (M), col = r (N)
  const bool isq = (n0 < 768);  // 256-aligned n0 -> block-uniform
  const float* bias = isq ? bias0 : bias1;
  unsigned short* outp = isq ? outq : outk;
  const int nb = isq ? n0 : (n0 - 768);
  // q scale: 1/8 softmax * log2(e) so attention uses native exp2 (exact id)
  const float scl = isq ? 0.18033688011112042f : 1.0f;
#pragma unroll
  for (int Nh = 0; Nh < 2; ++Nh)
#pragma unroll
    for (int nf = 0; nf < 4; ++nf) {
      const int n = nb + Nh * 128 + wc * 64 + nf * 16 + r;
      const float bv = bias[n];
#pragma unroll
      for (int Mh = 0; Mh < 2; ++Mh)
#pragma unroll
        for (int mf = 0; mf < 2; ++mf) {
          const int m = m0 + Mh * 128 + wr * 32 + mf * 16 + Q4 * 4;
#pragma unroll
          for (int g = 0; g < 4; ++g)
            outp[(size_t)(m + g) * 768 + n] =
                (unsigned short)bf16b((acc[Mh][Nh][mf][nf][g] + bv) * scl);
        }
    }
  if (!isq) {
    // kt permuted write: slot(s) = (s&~15) + ((s>>2)&1)*8 + ((s>>3)&1)*4 + (s&3)
    const int bq = m0 >> 10;
    const int sb0 = (m0 & 1023) + wr * 32 + (Q4 & 1) * 8 + (Q4 >> 1) * 4;
#pragma unroll
    for (int Nh = 0; Nh < 2; ++Nh)
#pragma unroll
      for (int nf = 0; nf < 4; ++nf) {
        const int nk = nb + Nh * 128 + wc * 64 + nf * 16 + r;
        const int hh = nk >> 6, dd = nk & 63;
        const float bv = bias1[nk];
#pragma unroll
        for (int Mh = 0; Mh < 2; ++Mh)
#pragma unroll
          for (int mf = 0; mf < 2; ++mf) {
            const int ns = sb0 + Mh * 128 + mf * 16;
            const float4v a4 = acc[Mh][Nh][mf][nf];
            unsigned lo = pack_hi16(rne_adj(a4[1] + bv), rne_adj(a4[0] + bv));
            unsigned hi = pack_hi16(rne_adj(a4[3] + bv), rne_adj(a4[2] + bv));
            *(U2*)(outkt + (size_t)((bq * 12 + hh) * 64 + dd) * 1024 + ns) =
                U2{lo, hi};
          }
      }
  }
}

// ---------------------------------------------------------------------------
// Out-proj GEMM, register-prefetch pipeline: out = ao*Wo^T + bo (fp32).
// 64x128 tile, BK=64, 12 iters, grid (6,128) = 768 blocks, 4 waves, 24 KB LDS.
// ---------------------------------------------------------------------------
__global__ __launch_bounds__(256, 3) void sgemm_out(
    const unsigned short* __restrict__ A, const unsigned short* __restrict__ B,
    const float* __restrict__ bias, float* __restrict__ outp) {
  __shared__ __align__(16) unsigned short a_l[4096];  // 64 rows x 64 k
  __shared__ __align__(16) unsigned short b_l[8192];  // 128 rows x 64 k
  const int tid = threadIdx.x;
  const int w = tid >> 6, lane = tid & 63;
  const int Q4 = lane >> 4, r = lane & 15;
  const int m0 = blockIdx.y * 64;
  const int n0 = blockIdx.x * 128;
  const int wm = w >> 1, wn = w & 1;

  float4v acc[2][4];
#pragma unroll
  for (int i = 0; i < 2; ++i)
#pragma unroll
    for (int j = 0; j < 4; ++j)
#pragma unroll
      for (int g = 0; g < 4; ++g) acc[i][j][g] = 0.0f;

  const unsigned short* Ab = A + (size_t)(m0 + r) * 768 + Q4 * 8;
  const unsigned short* Bb = B + (size_t)(n0 + r) * 768 + Q4 * 8;

  uint4v ra[2], rb[4];
  auto gload = [&](int kt) {
#pragma unroll
    for (int ci = 0; ci < 2; ++ci) {
      int idx = w * 2 + ci;
      ra[ci] = *(const uint4v*)(Ab + (idx >> 1) * 12288 + kt + (idx & 1) * 32);
    }
#pragma unroll
    for (int ci = 0; ci < 4; ++ci) {
      int idx = w * 4 + ci;
      rb[ci] = *(const uint4v*)(Bb + (idx >> 1) * 12288 + kt + (idx & 1) * 32);
    }
  };
  auto swrite = [&]() {
#pragma unroll
    for (int ci = 0; ci < 2; ++ci) {
      int idx = w * 2 + ci;
      *(uint4v*)&a_l[idx * 512 + lane * 8] = ra[ci];
    }
#pragma unroll
    for (int ci = 0; ci < 4; ++ci) {
      int idx = w * 4 + ci;
      *(uint4v*)&b_l[idx * 512 + lane * 8] = rb[ci];
    }
  };

  short8 af[2][2], bf[4][2];
  auto loadf = [&]() {
#pragma unroll
    for (int i = 0; i < 2; ++i)
#pragma unroll
      for (int ks = 0; ks < 2; ++ks)
        af[i][ks] = *(const short8*)&a_l[((wm * 2 + i) * 2 + ks) * 512 + lane * 8];
#pragma unroll
    for (int i = 0; i < 4; ++i)
#pragma unroll
      for (int ks = 0; ks < 2; ++ks)
        bf[i][ks] = *(const short8*)&b_l[((wn * 4 + i) * 2 + ks) * 512 + lane * 8];
  };
  auto dot = [&]() {
#pragma unroll
    for (int mt = 0; mt < 2; ++mt)
#pragma unroll
      for (int nt = 0; nt < 4; ++nt)
#pragma unroll
        for (int ks = 0; ks < 2; ++ks)
          acc[mt][nt] = __builtin_amdgcn_mfma_f32_16x16x32_bf16(
              af[mt][ks], bf[nt][ks], acc[mt][nt], 0, 0, 0);
  };

  gload(0);
#pragma unroll 1
  for (int t = 0; t < 12; ++t) {
    if (t > 0) BARRIER;
    swrite();
    if (t < 11) gload(t * 64 + 64);
    LGKM_WAIT;
    BARRIER;
    loadf();
    dot();
  }

#pragma unroll
  for (int nt = 0; nt < 4; ++nt) {
    int n = n0 + wn * 64 + nt * 16 + r;
    float bv = bias[n];
#pragma unroll
    for (int mt = 0; mt < 2; ++mt) {
      int m = m0 + wm * 32 + mt * 16 + Q4 * 4;
#pragma unroll
      for (int g = 0; g < 4; ++g)
        outp[(size_t)(m + g) * 768 + n] = acc[mt][nt][g] + bv;
    }
  }
}

// ---------------------------------------------------------------------------
// Flash attention, v = k, no-max softmax (scores bounded; exactly equivalent;
// q pre-scaled by 0.125*log2e so P = exp2(Sc) natively).
// Block = (b, h, 128 q-rows), 4 waves; wave owns 32 q-cols end-to-end.
// Sc^T = K * Q^T via 32x32x16 MFMA (C: col=q=lane&31, row=s=(reg&3)+8*(reg>>2)+4*hi)
// P = exp2(Sc) via raw v_exp_f32; v_cvt_pk_bf16_f32 pack into PV B-fragment.
// O^T = V^T * P^T.  l = 4 accumulator chains + deferred single shfl_xor.
// Q loads straight to bfq registers (R17); LDS 32KB; R12 counted-vmcnt
// schedule.  Ledger: entering iter t: [Vt(t):4]; after K-stage: vmcnt(4)
// lands Vt(t) before PV; after Vt-stage: vmcnt(4) lands K(t+1) before next
// QK.  t=7 drains Vt(7) with vmcnt(0).  T5 setprio around MFMAs.
// ---------------------------------------------------------------------------
__global__ __launch_bounds__(256, 3) void attn_fused(
    const unsigned short* __restrict__ qg,   // [8192][768], scaled bf16
    const unsigned short* __restrict__ kg,   // [8192][768]
    const unsigned short* __restrict__ ktg,  // [96][64][1024] perm s-order
    unsigned short* __restrict__ ao) {       // [8192][768]
  __shared__ __align__(16) unsigned short k_l[8192];   // 16 KB: 128s x 64d
  __shared__ __align__(16) unsigned short vt_l[8192];  // 16 KB: 64d x 128s(perm)

  const int tid = threadIdx.x;
  const int w = tid >> 6, lane = tid & 63;
  const int l31 = lane & 31, hi = lane >> 5;
  const int bid = blockIdx.x;
  const int b = bid & 7;                 // XCD-aligned: one batch per XCD
  const int h = bid >> 6;                // 0..11, slow -> L2 working set small
  const int qt = (bid >> 3) & 7;
  const int q0 = qt * 128;
  const int bh = b * 12 + h;

  // Q direct to registers (identity of the old q_l round-trip):
  short8 bfq[4];
  {
    const unsigned short* qp =
        qg + (size_t)(b * 1024 + q0 + w * 32 + l31) * 768 + h * 64 + hi * 8;
#pragma unroll
    for (int kb = 0; kb < 4; ++kb)
      bfq[kb] = *(const short8*)(qp + kb * 16);
  }

  // stage first K/Vt tiles; one-time full drain
#pragma unroll
  for (int ci = 0; ci < 4; ++ci) {
    int c = w * 4 + ci;
    async16(&k_l[c * 512 + lane * 8],
            kg + ((size_t)(b * 1024 + (c >> 2) * 32 + l31) * 768 + h * 64 + (c & 3) * 16 + hi * 8));
    async16(&vt_l[c * 512 + lane * 8],
            ktg + ((size_t)(bh * 64 + (c >> 3) * 32 + l31) * 1024 + (c & 7) * 16 + hi * 8));
  }
  __syncthreads();

  float16v o_acc[2];
#pragma unroll
  for (int db = 0; db < 2; ++db)
#pragma unroll
    for (int e = 0; e < 16; ++e) o_acc[db][e] = 0.0f;
  float ps0 = 0.0f, ps1 = 0.0f, ps2 = 0.0f, ps3 = 0.0f;

#pragma unroll 1
  for (int it = 0; it < 8; ++it) {
    // ---- QK phase: Sc^T = K * Q^T, 128 s x 32 q, 16 MFMA, 16 ds_read_b128
    float16v sc[4];
#pragma unroll
    for (int sb = 0; sb < 4; ++sb)
#pragma unroll
      for (int e = 0; e < 16; ++e) sc[sb][e] = 0.0f;
    __builtin_amdgcn_s_setprio(1);
#pragma unroll
    for (int sb = 0; sb < 4; ++sb)
#pragma unroll
      for (int kb = 0; kb < 4; ++kb) {
        short8 af = *(const short8*)&k_l[(sb * 4 + kb) * 512 + lane * 8];
        sc[sb] = __builtin_amdgcn_mfma_f32_32x32x16_bf16(af, bfq[kb], sc[sb], 0, 0, 0);
      }
    __builtin_amdgcn_s_setprio(0);

    BARRIER;  // all waves done reading k_l(it)
    if (it < 7) {
      const int s1 = (it + 1) * 128;
#pragma unroll
      for (int ci = 0; ci < 4; ++ci) {
        int c = w * 4 + ci;
        async16(&k_l[c * 512 + lane * 8],
                kg + ((size_t)(b * 1024 + s1 + (c >> 2) * 32 + l31) * 768 + h * 64 + (c & 3) * 16 + hi * 8));
      }
      vm_wait<4>();  // retires Vt(it); K(it+1) stays in flight
    } else {
      vm_wait<0>();  // drain Vt(7)
    }
    BARRIER;  // all waves' Vt(it) landed -> PV reads safe

    // ---- exp + PV phase: P = exp2(Sc); O^T += V^T * P^T (reads vt_l(it))
#pragma unroll
    for (int sb = 0; sb < 4; ++sb) {
      float pe[16];
#pragma unroll
      for (int e = 0; e < 16; ++e) pe[e] = __builtin_amdgcn_exp2f(sc[sb][e]);
#pragma unroll
      for (int e = 0; e < 16; e += 4) {
        ps0 += pe[e]; ps1 += pe[e + 1]; ps2 += pe[e + 2]; ps3 += pe[e + 3];
      }
      uint4v w0, w1;
#pragma unroll
      for (int p = 0; p < 4; ++p) {
        w0[p] = cvt_pk_bf16(pe[2 * p], pe[2 * p + 1]);
        w1[p] = cvt_pk_bf16(pe[2 * p + 8], pe[2 * p + 9]);
      }
      short8 pf0 = __builtin_bit_cast(short8, w0);
      short8 pf1 = __builtin_bit_cast(short8, w1);
      __builtin_amdgcn_s_setprio(1);
#pragma unroll
      for (int db = 0; db < 2; ++db) {
        short8 vf0 = *(const short8*)&vt_l[(db * 8 + sb * 2) * 512 + lane * 8];
        o_acc[db] = __builtin_amdgcn_mfma_f32_32x32x16_bf16(vf0, pf0, o_acc[db], 0, 0, 0);
        short8 vf1 = *(const short8*)&vt_l[(db * 8 + sb * 2 + 1) * 512 + lane * 8];
        o_acc[db] = __builtin_amdgcn_mfma_f32_32x32x16_bf16(vf1, pf1, o_acc[db], 0, 0, 0);
      }
      __builtin_amdgcn_s_setprio(0);
    }

    if (it < 7) {
      BARRIER;  // all waves done reading vt_l(it)
      const int s1 = (it + 1) * 128;
#pragma unroll
      for (int ci = 0; ci < 4; ++ci) {
        int c = w * 4 + ci;
        async16(&vt_l[c * 512 + lane * 8],
                ktg + ((size_t)(bh * 64 + (c >> 3) * 32 + l31) * 1024 + s1 + (c & 7) * 16 + hi * 8));
      }
      vm_wait<4>();  // retires K(it+1); Vt(it+1) stays in flight
      BARRIER;       // all waves' K(it+1) landed -> next QK safe
    }
  }

  // l: hi-halves hold complementary s-rows -> one xor-32 completes the sum
  float ps = (ps0 + ps1) + (ps2 + ps3);
  ps += __shfl_xor(ps, 32, 64);
  const float inv = 1.0f / ps;
  const size_t rowbase = (size_t)(b * 1024 + q0 + w * 32 + l31) * 768 + h * 64;
#pragma unroll
  for (int db = 0; db < 2; ++db)
#pragma unroll
    for (int qq = 0; qq < 4; ++qq) {
      unsigned lo = cvt_pk_bf16(o_acc[db][qq * 4 + 0] * inv,
                                o_acc[db][qq * 4 + 1] * inv);
      unsigned hh = cvt_pk_bf16(o_acc[db][qq * 4 + 2] * inv,
                                o_acc[db][qq * 4 + 3] * inv);
      *(U2*)(ao + rowbase + db * 32 + qq * 8 + hi * 4) = U2{lo, hh};
    }
}

// ---------------------------------------------------------------------------
extern "C" void kernel_launch(void* const* d_in, const int* in_sizes, int n_in,
                              void* d_out, int out_size, void* d_ws, size_t ws_size,
                              hipStream_t stream) {
  const float* x  = (const float*)d_in[0];
  const float* Wq = (const float*)d_in[1];
  const float* bq = (const float*)d_in[2];
  const float* Wk = (const float*)d_in[3];
  const float* bk = (const float*)d_in[4];
  const float* Wo = (const float*)d_in[5];
  const float* bo = (const float*)d_in[6];
  (void)in_sizes; (void)n_in; (void)out_size; (void)ws_size;

  // allow 128 KB dynamic LDS for sgemm_qk8 (one-time; host-side, capture-safe)
  static bool inited = false;
  if (!inited) {
    (void)hipFuncSetAttribute((const void*)sgemm_qk8,
                              hipFuncAttributeMaxDynamicSharedMemorySize, 131072);
    inited = true;
  }

  char* ws = (char*)d_ws;
  unsigned short* x_b   = (unsigned short*)(ws);              // 12,582,912 B
  unsigned short* wqk_b = (unsigned short*)(ws + 12582912);   //  2,359,296 B  [Wq;Wk]
  unsigned short* wo_b  = (unsigned short*)(ws + 14942208);   //  1,179,648 B
  unsigned short* q_b   = (unsigned short*)(ws + 16121856);   // 12,582,912 B
  unsigned short* k_b   = (unsigned short*)(ws + 28704768);   // 12,582,912 B
  unsigned short* kt_b  = (unsigned short*)(ws + 41287680);   // 12,582,912 B
  unsigned short* ao_b  = (unsigned short*)(ws + 53870592);   // 12,582,912 B

  // x + all three weight matrices in one launch
  cvt_all<<<3936, 256, 0, stream>>>(x, Wq, Wk, Wo,
                                    x_b, wqk_b, wqk_b + 589824, wo_b);

  // q = (x Wq^T + bq)*0.125*log2e (bf16), k = x Wk^T + bk (row-major + perm kt)
  sgemm_qk8<<<192, 512, 131072, stream>>>(x_b, wqk_b, bq, bk, q_b, k_b, kt_b);
  attn_fused<<<768, 256, 0, stream>>>(q_b, k_b, kt_b, ao_b);
  // out = ao Wo^T + bo (fp32)
  sgemm_out<<<dim3(6, 128), 256, 0, stream>>>(ao_b, wo_b, bo, (float*)d_out);
}